// Round 9
// baseline (457.458 us; speedup 1.0000x reference)
//
#include <hip/hip_runtime.h>
#include <stdint.h>

// Problem: B=16, D=512, H=64, W=64, M=512, N=B*H*W=65536
// out layout (floats):
//   updated_query  [0, 67108864) | updated_memory [67108864, 67371008)
//   score_q [67371008, 100925440) | score_m [100925440, 134479872)
//   separateness [134479872] | compactness [134479873]
#define UM_OFF   67108864u
#define SQ_OFF   67371008u
#define SM_OFF   100925440u
#define SEP_OFF  134479872u
#define COMP_OFF 134479873u

// ws layout (bytes)
#define WS_QBF   0u           // q bf16 (65536,512) 64 MiB -> 67108864
#define WS_EBF   67108864u    // E bf16 (65536,512) 64 MiB -> 134217728
#define WS_KBF   134217728u   // keys bf16 -> 134742016
#define WS_KTBF  134742016u   // keysT bf16 -> 135266304
#define WS_G     135266304u   // g[r] int32 -> 135528448
#define WS_W     135528448u   // wgt[r] f32 -> 135790592
#define WS_RSUM  135790592u   // rsum[r] f32 -> 136052736
#define WS_CSUM  136052736u   // csum f32 (512) -> 136054784
#define WS_KN2   136054784u   // ||k_m||^2 f32 (512) -> 136056832
#define WS_KSM   136056832u   // sum(k_m) f32 (512) -> 136058880
#define WS_QSUM  136058880u   // sum(q_r) f32 (65536) -> 136321024

typedef __attribute__((ext_vector_type(8))) short short8v;
typedef __attribute__((ext_vector_type(4))) float float4v;

__device__ __forceinline__ unsigned short f2bf(float f) {
  union { float f; uint32_t u; } v; v.f = f;
  return (unsigned short)((v.u + 0x7fffu + ((v.u >> 16) & 1u)) >> 16);
}
__device__ __forceinline__ float bf2f(unsigned short s) {
  union { uint32_t u; float f; } v; v.u = ((uint32_t)s) << 16;
  return v.f;
}

#define GLDS16(gp, lp) __builtin_amdgcn_global_load_lds( \
    (__attribute__((address_space(1))) const void*)(gp), \
    (__attribute__((address_space(3))) void*)(lp), 16, 0, 0)

// ---------------- K01: fused prep + per-pixel L2 norm ----------------
// blocks [0,1024): norm work (one per (b,h)); blocks [1024,1536): keys prep
__global__ __launch_bounds__(512) void k01_prep_norm(
    const float* __restrict__ query, const float* __restrict__ keys,
    unsigned short* __restrict__ kbf, unsigned short* __restrict__ ktbf,
    float* __restrict__ csum, float* __restrict__ rsum,
    float* __restrict__ kn2, float* __restrict__ ksm,
    unsigned short* __restrict__ qbf, float* __restrict__ qsum,
    float* __restrict__ out) {
  int tid = threadIdx.x;
  if (blockIdx.x >= 1024) {
    __shared__ float pn[8], ps[8];
    int b = blockIdx.x - 1024;   // key row
    int t = tid;                 // col
    int i = b * 512 + t;
    float v = keys[i];
    kbf[i] = f2bf(v);
    ktbf[i] = f2bf(keys[(size_t)t * 512 + b]);
    float s1 = v, s2 = v * v;
    #pragma unroll
    for (int off = 1; off < 64; off <<= 1) {
      s1 += __shfl_xor(s1, off);
      s2 += __shfl_xor(s2, off);
    }
    if ((t & 63) == 0) { pn[t >> 6] = s2; ps[t >> 6] = s1; }
    __syncthreads();
    if (t == 0) {
      float n2 = 0.f, sm = 0.f;
      #pragma unroll
      for (int g = 0; g < 8; ++g) { n2 += pn[g]; sm += ps[g]; }
      kn2[b] = n2; ksm[b] = sm;
    }
    if (i < 65536) rsum[i] = 0.0f;
    if (i < 512) csum[i] = 0.0f;
    if (i < 2) out[SEP_OFF + i] = 0.0f;
    return;
  }
  __shared__ unsigned short vals[512 * 65];
  __shared__ float pp[8][64];
  __shared__ float rs[64];
  int bh = blockIdx.x;                       // b*64 + h
  int b = bh >> 6, h = bh & 63;
  int w = tid & 63, dg = tid >> 6;           // 8 d-groups of 64
  const float* src = query + ((size_t)(b * 512) * 64 + h) * 64 + w;
  float ss = 0.f;
  #pragma unroll 4
  for (int i = 0; i < 64; ++i) {
    int d = dg * 64 + i;
    float v = src[(size_t)d * 4096];
    ss += v * v;
    vals[d * 65 + w] = f2bf(v);
  }
  pp[dg][w] = ss;
  __syncthreads();
  if (tid < 64) {
    float s = 0.f;
    #pragma unroll
    for (int g = 0; g < 8; ++g) s += pp[g][tid];
    rs[tid] = 1.0f / fmaxf(sqrtf(s), 1e-12f);
  }
  __syncthreads();
  float rw_ = rs[w];
  float* dst = out + ((size_t)(b * 1024) * 64 + h) * 64 + w;
  #pragma unroll 4
  for (int i = 0; i < 64; ++i) {
    int d = dg * 64 + i;
    __builtin_nontemporal_store(bf2f(vals[d * 65 + w]) * rw_, &dst[(size_t)d * 4096]);
  }
  // phase C: qbf[r][d], r = bh*64 + w2; also row-sum of qn
  int w2 = tid >> 3, dc = tid & 7;
  float rw = rs[w2];
  unsigned short* qrow = qbf + ((size_t)bh * 64 + w2) * 512;
  float qs = 0.f;
  #pragma unroll
  for (int g = 0; g < 8; ++g) {
    int d0 = g * 64 + dc * 8;
    short8v pk;
    #pragma unroll
    for (int jj = 0; jj < 8; ++jj) {
      float qn = bf2f(vals[(d0 + jj) * 65 + w2]) * rw;
      qs += qn;
      pk[jj] = (short)f2bf(qn);
    }
    __builtin_nontemporal_store(pk, (short8v*)(qrow + d0));
  }
  qs += __shfl_xor(qs, 1); qs += __shfl_xor(qs, 2); qs += __shfl_xor(qs, 4);
  if (dc == 0) qsum[bh * 64 + w2] = qs;
}

// ---------------- K3: GEMM1 -> Ebf (nt), csum + rsum atomics; 2-kt-per-barrier ----------------
__global__ __launch_bounds__(256) void k3_gemm1(
    const unsigned short* __restrict__ qbf, const unsigned short* __restrict__ kbf,
    unsigned short* __restrict__ ebf, float* __restrict__ csum, float* __restrict__ rsum) {
  __shared__ unsigned short As[2][128 * 32];
  __shared__ unsigned short Bs[2][128 * 32];
  int bid = blockIdx.x;                          // 2048
  int bm = (bid & 7) * 64 + (bid >> 5);          // XCD siblings share B panel
  int bn = (bid >> 3) & 3;
  int tid = threadIdx.x;
  int lane = tid & 63, wid = tid >> 6;
  int wr = wid >> 1, wc = wid & 1;
  float4v acc[4][4];
  #pragma unroll
  for (int m = 0; m < 4; ++m)
    #pragma unroll
    for (int n = 0; n < 4; ++n) acc[m][n] = (float4v){0.f, 0.f, 0.f, 0.f};
  const unsigned short* Abase = qbf + (size_t)bm * 128 * 512;
  const unsigned short* Bbase = kbf + (size_t)bn * 128 * 512;
  int u0 = wid * 128 + lane, u1 = u0 + 64;
  int ra0 = u0 >> 2, ca0 = (u0 & 3) * 8;
  int ra1 = u1 >> 2, ca1 = (u1 & 3) * 8;
  for (int kt2 = 0; kt2 < 8; ++kt2) {
    #pragma unroll
    for (int s = 0; s < 2; ++s) {
      const unsigned short* Ak = Abase + (kt2 * 2 + s) * 32;
      const unsigned short* Bk = Bbase + (kt2 * 2 + s) * 32;
      GLDS16(Ak + (size_t)ra0 * 512 + ca0, &As[s][(wid * 2 + 0) * 512]);
      GLDS16(Ak + (size_t)ra1 * 512 + ca1, &As[s][(wid * 2 + 1) * 512]);
      GLDS16(Bk + (size_t)ra0 * 512 + ca0, &Bs[s][(wid * 2 + 0) * 512]);
      GLDS16(Bk + (size_t)ra1 * 512 + ca1, &Bs[s][(wid * 2 + 1) * 512]);
    }
    __syncthreads();
    #pragma unroll
    for (int s = 0; s < 2; ++s) {
      short8v a[4], b[4];
      const unsigned short* pa = &As[s][0] + (wr * 64 + (lane & 15)) * 32 + (lane >> 4) * 8;
      const unsigned short* pb = &Bs[s][0] + (wc * 64 + (lane & 15)) * 32 + (lane >> 4) * 8;
      #pragma unroll
      for (int m = 0; m < 4; ++m) a[m] = *(const short8v*)(pa + m * 512);
      #pragma unroll
      for (int n = 0; n < 4; ++n) b[n] = *(const short8v*)(pb + n * 512);
      #pragma unroll
      for (int m = 0; m < 4; ++m)
        #pragma unroll
        for (int n = 0; n < 4; ++n)
          acc[m][n] = __builtin_amdgcn_mfma_f32_16x16x32_bf16(a[m], b[n], acc[m][n], 0, 0, 0);
    }
    __syncthreads();
  }
  // epilogue: Ebf = bf16(exp(logit/scale)) nt scatter; csum + rsum atomics
  const float inv_scale = 0.44194173824159216f;  // 1/(sqrt(512)*0.1)
  int r0 = bm * 128 + wr * 64 + (lane >> 4) * 4;
  int c0 = bn * 128 + wc * 64 + (lane & 15);
  float cs[4] = {0.f, 0.f, 0.f, 0.f};
  float rp[4][4];
  #pragma unroll
  for (int m = 0; m < 4; ++m)
    #pragma unroll
    for (int j = 0; j < 4; ++j) rp[m][j] = 0.f;
  #pragma unroll
  for (int m = 0; m < 4; ++m)
    #pragma unroll
    for (int n = 0; n < 4; ++n)
      #pragma unroll
      for (int j = 0; j < 4; ++j) {
        float v = __expf(acc[m][n][j] * inv_scale);
        __builtin_nontemporal_store(f2bf(v),
            &ebf[(size_t)(r0 + m * 16 + j) * 512 + c0 + n * 16]);
        cs[n] += v;
        rp[m][j] += v;
      }
  #pragma unroll
  for (int n = 0; n < 4; ++n) {
    float v = cs[n];
    v += __shfl_xor(v, 16);
    v += __shfl_xor(v, 32);
    if ((lane >> 4) == 0) atomicAdd(&csum[c0 + n * 16], v);
  }
  #pragma unroll
  for (int m = 0; m < 4; ++m)
    #pragma unroll
    for (int j = 0; j < 4; ++j) {
      float v = rp[m][j];
      v += __shfl_xor(v, 1); v += __shfl_xor(v, 2);
      v += __shfl_xor(v, 4); v += __shfl_xor(v, 8);
      rp[m][j] = v;
    }
  int g16 = lane & 15;
  float myrp = 0.f;
  #pragma unroll
  for (int m = 0; m < 4; ++m)
    #pragma unroll
    for (int j = 0; j < 4; ++j)
      if (g16 == m * 4 + j) myrp = rp[m][j];
  atomicAdd(&rsum[r0 + (g16 >> 2) * 16 + (g16 & 3)], myrp);
}

// ---------------- K5: GEMM2 fused with the per-row pass; 2-kt-per-barrier ----------------
__global__ __launch_bounds__(256) void k5_fused(
    const unsigned short* __restrict__ ktbf, const unsigned short* __restrict__ ebf,
    const float* __restrict__ rsum, const float* __restrict__ csum,
    const float* __restrict__ qsum, const float* __restrict__ kn2,
    const float* __restrict__ ksm, int* __restrict__ gidx, float* __restrict__ gw,
    float* __restrict__ out) {
  __shared__ unsigned short As[2][128 * 32];
  __shared__ unsigned short Bs[2][128 * 32];
  int bid = blockIdx.x;                              // 2048
  int g = (bid & 7) * 64 + (bid >> 5);               // (b,nt); XCD siblings share B panel
  int b = g >> 5, nt = g & 31, dt = (bid >> 3) & 3;
  int tid = threadIdx.x;
  int lane = tid & 63, wid = tid >> 6;
  int wr = wid >> 1, wc = wid & 1;
  float4v acc[4][4];
  #pragma unroll
  for (int m = 0; m < 4; ++m)
    #pragma unroll
    for (int n = 0; n < 4; ++n) acc[m][n] = (float4v){0.f, 0.f, 0.f, 0.f};
  const unsigned short* Abase = ktbf + (size_t)dt * 128 * 512;
  size_t brow0 = (size_t)g * 128;
  int u0 = wid * 128 + lane, u1 = u0 + 64;
  int ra0 = u0 >> 2, ca0 = (u0 & 3) * 8;
  int ra1 = u1 >> 2, ca1 = (u1 & 3) * 8;
  for (int kt2 = 0; kt2 < 8; ++kt2) {
    #pragma unroll
    for (int s = 0; s < 2; ++s) {
      int kt = kt2 * 2 + s;
      GLDS16(Abase + (size_t)ra0 * 512 + kt * 32 + ca0, &As[s][(wid * 2 + 0) * 512]);
      GLDS16(Abase + (size_t)ra1 * 512 + kt * 32 + ca1, &As[s][(wid * 2 + 1) * 512]);
      GLDS16(ebf + (brow0 + ra0) * 512 + kt * 32 + ca0, &Bs[s][(wid * 2 + 0) * 512]);
      GLDS16(ebf + (brow0 + ra1) * 512 + kt * 32 + ca1, &Bs[s][(wid * 2 + 1) * 512]);
    }
    __syncthreads();
    #pragma unroll
    for (int s = 0; s < 2; ++s) {
      short8v a[4], bb[4];
      const unsigned short* pa = &As[s][0] + (wr * 64 + (lane & 15)) * 32 + (lane >> 4) * 8;
      const unsigned short* pb = &Bs[s][0] + (wc * 64 + (lane & 15)) * 32 + (lane >> 4) * 8;
      #pragma unroll
      for (int m = 0; m < 4; ++m) a[m] = *(const short8v*)(pa + m * 512);
      #pragma unroll
      for (int n = 0; n < 4; ++n) bb[n] = *(const short8v*)(pb + n * 512);
      #pragma unroll
      for (int m = 0; m < 4; ++m)
        #pragma unroll
        for (int n = 0; n < 4; ++n)
          acc[m][n] = __builtin_amdgcn_mfma_f32_16x16x32_bf16(a[m], bb[n], acc[m][n], 0, 0, 0);
    }
    __syncthreads();
  }
  // GEMM epilogue: out[b, 512 + d, hw], scaled by 1/rsum[col-row] (nt stores)
  {
    float* dst = out + (size_t)b * 4194304 + (size_t)512 * 4096;
    int d0 = dt * 128 + wr * 64 + (lane >> 4) * 4;
    int c0 = nt * 128 + wc * 64 + (lane & 15);
    float invc[4];
    #pragma unroll
    for (int n = 0; n < 4; ++n) invc[n] = 1.0f / rsum[b * 4096 + c0 + n * 16];
    #pragma unroll
    for (int m = 0; m < 4; ++m)
      #pragma unroll
      for (int n = 0; n < 4; ++n)
        #pragma unroll
        for (int j = 0; j < 4; ++j)
          __builtin_nontemporal_store(acc[m][n][j] * invc[n],
              &dst[(size_t)(d0 + m * 16 + j) * 4096 + (c0 + n * 16)]);
  }
  // Row phase: rows [g*128 + dt*32, +32), 8 per wave (Ebf rows are L2-hot)
  float4v cA = *(const float4v*)(csum + lane * 8);
  float4v cB = *(const float4v*)(csum + lane * 8 + 4);
  float4v rcA, rcB;
  #pragma unroll
  for (int j = 0; j < 4; ++j) { rcA[j] = 1.0f / cA[j]; rcB[j] = 1.0f / cB[j]; }
  float closs = 0.f, sloss = 0.f;
  const float S2 = 4.525483399593904f;   // 2*sqrt(512)*0.1
  int r_base = g * 128 + dt * 32 + wid * 8;
  for (int it = 0; it < 8; ++it) {
    int r = r_base + it;
    short8v eb = *(const short8v*)(ebf + (size_t)r * 512 + lane * 8);
    float e[8];
    #pragma unroll
    for (int j = 0; j < 8; ++j) e[j] = bf2f((unsigned short)eb[j]);
    float invr = 1.0f / rsum[r];          // exact f32 row sum from k3
    // top-2 (ties -> lower index)
    float v1 = -1.f, v2 = -2.f; int i1 = 0, i2 = 0;
    #pragma unroll
    for (int j = 0; j < 8; ++j) {
      float val = e[j]; int idx = lane * 8 + j;
      if (val > v1) { v2 = v1; i2 = i1; v1 = val; i1 = idx; }
      else if (val > v2) { v2 = val; i2 = idx; }
    }
    #pragma unroll
    for (int off = 1; off < 64; off <<= 1) {
      float ov1 = __shfl_xor(v1, off); int oi1 = __shfl_xor(i1, off);
      float ov2 = __shfl_xor(v2, off); int oi2 = __shfl_xor(i2, off);
      bool take = (ov1 > v1) || (ov1 == v1 && oi1 < i1);
      float av = take ? v1 : v2;  int ai = take ? i1 : i2;
      float bv = take ? ov2 : ov1; int bi = take ? oi2 : oi1;
      bool t2 = (bv > av) || (bv == av && bi < ai);
      v2 = t2 ? bv : av; i2 = t2 ? bi : ai;
      v1 = take ? ov1 : v1; i1 = take ? oi1 : i1;
    }
    float* SQrow = out + SQ_OFF + (size_t)r * 512;
    float* SMrow = out + SM_OFF + (size_t)r * 512;
    float4v sq0, sq1, sm0, sm1;
    #pragma unroll
    for (int j = 0; j < 4; ++j) {
      sq0[j] = e[j] * rcA[j];     sq1[j] = e[4 + j] * rcB[j];
      sm0[j] = e[j] * invr;       sm1[j] = e[4 + j] * invr;
    }
    __builtin_nontemporal_store(sq0, (float4v*)(SQrow + lane * 8));
    __builtin_nontemporal_store(sq1, (float4v*)(SQrow + lane * 8 + 4));
    __builtin_nontemporal_store(sm0, (float4v*)(SMrow + lane * 8));
    __builtin_nontemporal_store(sm1, (float4v*)(SMrow + lane * 8 + 4));
    // closed-form losses: ||q||=1, q·k_i = s*ln(E_i)
    float qs = qsum[r];
    float cp_row = 1.0f + kn2[i1] - S2 * __logf(v1);
    float dp2 = cp_row + 2e-6f * (qs - ksm[i1]) + 5.12e-10f;
    float cn_row = 1.0f + kn2[i2] - S2 * __logf(v2);
    float dn2 = cn_row + 2e-6f * (qs - ksm[i2]) + 5.12e-10f;
    closs += cp_row;
    sloss += fmaxf(sqrtf(dp2) - sqrtf(dn2) + 1.0f, 0.f);
    if (lane == 0) { gidx[r] = i1; gw[r] = v1 / csum[i1]; }
  }
  if (lane == 0) {
    atomicAdd(out + SEP_OFF, sloss * (1.0f / 65536.0f));
    atomicAdd(out + COMP_OFF, closs * (1.0f / (65536.0f * 512.0f)));
  }
}

// ---------------- K4b: segment gather + memory update (2 slots per block) ----------------
__global__ __launch_bounds__(512) void k4b_gather(
    const int* __restrict__ gidx, const float* __restrict__ gw,
    const unsigned short* __restrict__ qbf, const float* __restrict__ keys,
    float* __restrict__ out) {
  __shared__ float red[8][512];
  __shared__ float wss[2][8];
  int m0 = blockIdx.x * 2, m1 = m0 + 1;   // 256 blocks
  int tid = threadIdx.x, lane = tid & 63, wid = tid >> 6;
  float acc0[8] = {0.f, 0.f, 0.f, 0.f, 0.f, 0.f, 0.f, 0.f};
  float acc1[8] = {0.f, 0.f, 0.f, 0.f, 0.f, 0.f, 0.f, 0.f};
  for (int c = 0; c < 128; ++c) {
    int r0 = wid * 8192 + c * 64;
    int gv = gidx[r0 + lane];
    unsigned long long mask0 = __ballot(gv == m0);
    unsigned long long mask1 = __ballot(gv == m1);
    while (mask0) {
      int bb = __ffsll((long long)mask0) - 1;
      mask0 &= mask0 - 1;
      int r = r0 + bb;
      float wv = gw[r];
      short8v qv = *(const short8v*)(qbf + (size_t)r * 512 + lane * 8);
      #pragma unroll
      for (int j = 0; j < 8; ++j) acc0[j] += wv * bf2f((unsigned short)qv[j]);
    }
    while (mask1) {
      int bb = __ffsll((long long)mask1) - 1;
      mask1 &= mask1 - 1;
      int r = r0 + bb;
      float wv = gw[r];
      short8v qv = *(const short8v*)(qbf + (size_t)r * 512 + lane * 8);
      #pragma unroll
      for (int j = 0; j < 8; ++j) acc1[j] += wv * bf2f((unsigned short)qv[j]);
    }
  }
  // reduce m0
  #pragma unroll
  for (int j = 0; j < 8; ++j) red[wid][lane * 8 + j] = acc0[j];
  __syncthreads();
  float s0 = 0.f;
  #pragma unroll
  for (int gg = 0; gg < 8; ++gg) s0 += red[gg][tid];
  __syncthreads();
  // reduce m1
  #pragma unroll
  for (int j = 0; j < 8; ++j) red[wid][lane * 8 + j] = acc1[j];
  __syncthreads();
  float s1 = 0.f;
  #pragma unroll
  for (int gg = 0; gg < 8; ++gg) s1 += red[gg][tid];
  // memory update for both slots
  float v0 = keys[(size_t)m0 * 512 + tid] * 0.999f + s0 * 0.001f;
  float v1 = keys[(size_t)m1 * 512 + tid] * 0.999f + s1 * 0.001f;
  float ssa = v0 * v0, ssb = v1 * v1;
  #pragma unroll
  for (int off = 1; off < 64; off <<= 1) {
    ssa += __shfl_xor(ssa, off);
    ssb += __shfl_xor(ssb, off);
  }
  if (lane == 0) { wss[0][wid] = ssa; wss[1][wid] = ssb; }
  __syncthreads();
  float t0 = 0.f, t1 = 0.f;
  #pragma unroll
  for (int gg = 0; gg < 8; ++gg) { t0 += wss[0][gg]; t1 += wss[1][gg]; }
  out[UM_OFF + (size_t)m0 * 512 + tid] = v0 * (1.0f / fmaxf(sqrtf(t0), 1e-12f));
  out[UM_OFF + (size_t)m1 * 512 + tid] = v1 * (1.0f / fmaxf(sqrtf(t1), 1e-12f));
}

extern "C" void kernel_launch(void* const* d_in, const int* in_sizes, int n_in,
                              void* d_out, int out_size, void* d_ws, size_t ws_size,
                              hipStream_t stream) {
  const float* query = (const float*)d_in[0];
  const float* keys  = (const float*)d_in[1];
  float* out = (float*)d_out;
  char* ws = (char*)d_ws;
  unsigned short* qbf  = (unsigned short*)(ws + WS_QBF);
  unsigned short* ebf  = (unsigned short*)(ws + WS_EBF);
  unsigned short* kbf  = (unsigned short*)(ws + WS_KBF);
  unsigned short* ktbf = (unsigned short*)(ws + WS_KTBF);
  int*   gidx = (int*)(ws + WS_G);
  float* gw   = (float*)(ws + WS_W);
  float* rsum = (float*)(ws + WS_RSUM);
  float* csum = (float*)(ws + WS_CSUM);
  float* kn2  = (float*)(ws + WS_KN2);
  float* ksm  = (float*)(ws + WS_KSM);
  float* qsum = (float*)(ws + WS_QSUM);

  k01_prep_norm<<<dim3(1536), dim3(512), 0, stream>>>(
      query, keys, kbf, ktbf, csum, rsum, kn2, ksm, qbf, qsum, out);
  k3_gemm1<<<dim3(2048), dim3(256), 0, stream>>>(qbf, kbf, ebf, csum, rsum);
  k5_fused<<<dim3(2048), dim3(256), 0, stream>>>(
      ktbf, ebf, rsum, csum, qsum, kn2, ksm, gidx, gw, out);
  k4b_gather<<<dim3(256), dim3(512), 0, stream>>>(gidx, gw, qbf, keys, out);
}

// Round 10
// 402.692 us; speedup vs baseline: 1.1360x; 1.1360x over previous
//
#include <hip/hip_runtime.h>
#include <stdint.h>

// Problem: B=16, D=512, H=64, W=64, M=512, N=B*H*W=65536
// out layout (floats):
//   updated_query  [0, 67108864) | updated_memory [67108864, 67371008)
//   score_q [67371008, 100925440) | score_m [100925440, 134479872)
//   separateness [134479872] | compactness [134479873]
#define UM_OFF   67108864u
#define SQ_OFF   67371008u
#define SM_OFF   100925440u
#define SEP_OFF  134479872u
#define COMP_OFF 134479873u

// ws layout (bytes)
#define WS_QBF   0u           // q bf16 (65536,512) 64 MiB -> 67108864
#define WS_EBF   67108864u    // E bf16 (65536,512) 64 MiB -> 134217728
#define WS_KBF   134217728u   // keys bf16 -> 134742016
#define WS_KTBF  134742016u   // keysT bf16 -> 135266304
#define WS_W     135266304u   // wgt[r] f32 -> 135528448
#define WS_RSUM  135528448u   // rsum[r] f32 -> 135790592
#define WS_CSUM  135790592u   // csum f32 (512) -> 135792640
#define WS_KN2   135792640u   // ||k_m||^2 f32 (512) -> 135794688
#define WS_KSM   135794688u   // sum(k_m) f32 (512) -> 135796736
#define WS_CNT   135796736u   // per-slot count int32 (512) -> 135798784
#define WS_QSUM  135798784u   // sum(q_r) f32 (65536) -> 136060928
#define WS_LIST  136060928u   // row lists int32 (512 x 1024) 2 MiB -> 138158080

typedef __attribute__((ext_vector_type(8))) short short8v;
typedef __attribute__((ext_vector_type(4))) float float4v;

__device__ __forceinline__ unsigned short f2bf(float f) {
  union { float f; uint32_t u; } v; v.f = f;
  return (unsigned short)((v.u + 0x7fffu + ((v.u >> 16) & 1u)) >> 16);
}
__device__ __forceinline__ float bf2f(unsigned short s) {
  union { uint32_t u; float f; } v; v.u = ((uint32_t)s) << 16;
  return v.f;
}

#define GLDS16(gp, lp) __builtin_amdgcn_global_load_lds( \
    (__attribute__((address_space(1))) const void*)(gp), \
    (__attribute__((address_space(3))) void*)(lp), 16, 0, 0)

// ---------------- K01: fused prep + per-pixel L2 norm ----------------
// blocks [0,1024): norm work (one per (b,h)); blocks [1024,1536): keys prep
__global__ __launch_bounds__(512) void k01_prep_norm(
    const float* __restrict__ query, const float* __restrict__ keys,
    unsigned short* __restrict__ kbf, unsigned short* __restrict__ ktbf,
    float* __restrict__ csum, float* __restrict__ rsum,
    float* __restrict__ kn2, float* __restrict__ ksm, int* __restrict__ cnt,
    unsigned short* __restrict__ qbf, float* __restrict__ qsum,
    float* __restrict__ out) {
  int tid = threadIdx.x;
  if (blockIdx.x >= 1024) {
    __shared__ float pn[8], ps[8];
    int b = blockIdx.x - 1024;   // key row
    int t = tid;                 // col
    int i = b * 512 + t;
    float v = keys[i];
    kbf[i] = f2bf(v);
    ktbf[i] = f2bf(keys[(size_t)t * 512 + b]);
    float s1 = v, s2 = v * v;
    #pragma unroll
    for (int off = 1; off < 64; off <<= 1) {
      s1 += __shfl_xor(s1, off);
      s2 += __shfl_xor(s2, off);
    }
    if ((t & 63) == 0) { pn[t >> 6] = s2; ps[t >> 6] = s1; }
    __syncthreads();
    if (t == 0) {
      float n2 = 0.f, sm = 0.f;
      #pragma unroll
      for (int g = 0; g < 8; ++g) { n2 += pn[g]; sm += ps[g]; }
      kn2[b] = n2; ksm[b] = sm;
    }
    if (i < 65536) rsum[i] = 0.0f;
    if (i < 512) { csum[i] = 0.0f; cnt[i] = 0; }
    if (i < 2) out[SEP_OFF + i] = 0.0f;
    return;
  }
  __shared__ unsigned short vals[512 * 65];
  __shared__ float pp[8][64];
  __shared__ float rs[64];
  int bh = blockIdx.x;                       // b*64 + h
  int b = bh >> 6, h = bh & 63;
  int w = tid & 63, dg = tid >> 6;           // 8 d-groups of 64
  const float* src = query + ((size_t)(b * 512) * 64 + h) * 64 + w;
  float ss = 0.f;
  #pragma unroll 4
  for (int i = 0; i < 64; ++i) {
    int d = dg * 64 + i;
    float v = src[(size_t)d * 4096];
    ss += v * v;
    vals[d * 65 + w] = f2bf(v);
  }
  pp[dg][w] = ss;
  __syncthreads();
  if (tid < 64) {
    float s = 0.f;
    #pragma unroll
    for (int g = 0; g < 8; ++g) s += pp[g][tid];
    rs[tid] = 1.0f / fmaxf(sqrtf(s), 1e-12f);
  }
  __syncthreads();
  float rw_ = rs[w];
  float* dst = out + ((size_t)(b * 1024) * 64 + h) * 64 + w;
  #pragma unroll 4
  for (int i = 0; i < 64; ++i) {
    int d = dg * 64 + i;
    __builtin_nontemporal_store(bf2f(vals[d * 65 + w]) * rw_, &dst[(size_t)d * 4096]);
  }
  // phase C: qbf[r][d], r = bh*64 + w2; also row-sum of qn
  int w2 = tid >> 3, dc = tid & 7;
  float rw = rs[w2];
  unsigned short* qrow = qbf + ((size_t)bh * 64 + w2) * 512;
  float qs = 0.f;
  #pragma unroll
  for (int g = 0; g < 8; ++g) {
    int d0 = g * 64 + dc * 8;
    short8v pk;
    #pragma unroll
    for (int jj = 0; jj < 8; ++jj) {
      float qn = bf2f(vals[(d0 + jj) * 65 + w2]) * rw;
      qs += qn;
      pk[jj] = (short)f2bf(qn);
    }
    *(short8v*)(qrow + d0) = pk;
  }
  qs += __shfl_xor(qs, 1); qs += __shfl_xor(qs, 2); qs += __shfl_xor(qs, 4);
  if (dc == 0) qsum[bh * 64 + w2] = qs;
}

// ---------------- K3: GEMM1 -> Ebf, csum + rsum atomics ----------------
__global__ __launch_bounds__(256) void k3_gemm1(
    const unsigned short* __restrict__ qbf, const unsigned short* __restrict__ kbf,
    unsigned short* __restrict__ ebf, float* __restrict__ csum, float* __restrict__ rsum) {
  __shared__ unsigned short As[128 * 32];
  __shared__ unsigned short Bs[128 * 32];
  int bid = blockIdx.x;                          // 2048
  int bm = (bid & 7) * 64 + (bid >> 5);          // XCD siblings share B panel
  int bn = (bid >> 3) & 3;
  int tid = threadIdx.x;
  int lane = tid & 63, wid = tid >> 6;
  int wr = wid >> 1, wc = wid & 1;
  float4v acc[4][4];
  #pragma unroll
  for (int m = 0; m < 4; ++m)
    #pragma unroll
    for (int n = 0; n < 4; ++n) acc[m][n] = (float4v){0.f, 0.f, 0.f, 0.f};
  const unsigned short* Abase = qbf + (size_t)bm * 128 * 512;
  const unsigned short* Bbase = kbf + (size_t)bn * 128 * 512;
  int u0 = wid * 128 + lane, u1 = u0 + 64;
  int ra0 = u0 >> 2, ca0 = (u0 & 3) * 8;
  int ra1 = u1 >> 2, ca1 = (u1 & 3) * 8;
  for (int kt = 0; kt < 16; ++kt) {
    const unsigned short* Ak = Abase + kt * 32;
    const unsigned short* Bk = Bbase + kt * 32;
    GLDS16(Ak + (size_t)ra0 * 512 + ca0, &As[(wid * 2 + 0) * 512]);
    GLDS16(Ak + (size_t)ra1 * 512 + ca1, &As[(wid * 2 + 1) * 512]);
    GLDS16(Bk + (size_t)ra0 * 512 + ca0, &Bs[(wid * 2 + 0) * 512]);
    GLDS16(Bk + (size_t)ra1 * 512 + ca1, &Bs[(wid * 2 + 1) * 512]);
    __syncthreads();
    short8v a[4], b[4];
    const unsigned short* pa = As + (wr * 64 + (lane & 15)) * 32 + (lane >> 4) * 8;
    const unsigned short* pb = Bs + (wc * 64 + (lane & 15)) * 32 + (lane >> 4) * 8;
    #pragma unroll
    for (int m = 0; m < 4; ++m) a[m] = *(const short8v*)(pa + m * 512);
    #pragma unroll
    for (int n = 0; n < 4; ++n) b[n] = *(const short8v*)(pb + n * 512);
    #pragma unroll
    for (int m = 0; m < 4; ++m)
      #pragma unroll
      for (int n = 0; n < 4; ++n)
        acc[m][n] = __builtin_amdgcn_mfma_f32_16x16x32_bf16(a[m], b[n], acc[m][n], 0, 0, 0);
    __syncthreads();
  }
  // epilogue: Ebf = bf16(exp(logit/scale)); csum + rsum atomics
  const float inv_scale = 0.44194173824159216f;  // 1/(sqrt(512)*0.1)
  int r0 = bm * 128 + wr * 64 + (lane >> 4) * 4;
  int c0 = bn * 128 + wc * 64 + (lane & 15);
  float cs[4] = {0.f, 0.f, 0.f, 0.f};
  float rp[4][4];
  #pragma unroll
  for (int m = 0; m < 4; ++m)
    #pragma unroll
    for (int j = 0; j < 4; ++j) rp[m][j] = 0.f;
  #pragma unroll
  for (int m = 0; m < 4; ++m)
    #pragma unroll
    for (int n = 0; n < 4; ++n)
      #pragma unroll
      for (int j = 0; j < 4; ++j) {
        float v = __expf(acc[m][n][j] * inv_scale);
        ebf[(size_t)(r0 + m * 16 + j) * 512 + c0 + n * 16] = f2bf(v);
        cs[n] += v;
        rp[m][j] += v;
      }
  #pragma unroll
  for (int n = 0; n < 4; ++n) {
    float v = cs[n];
    v += __shfl_xor(v, 16);
    v += __shfl_xor(v, 32);
    if ((lane >> 4) == 0) atomicAdd(&csum[c0 + n * 16], v);
  }
  #pragma unroll
  for (int m = 0; m < 4; ++m)
    #pragma unroll
    for (int j = 0; j < 4; ++j) {
      float v = rp[m][j];
      v += __shfl_xor(v, 1); v += __shfl_xor(v, 2);
      v += __shfl_xor(v, 4); v += __shfl_xor(v, 8);
      rp[m][j] = v;
    }
  int g16 = lane & 15;
  float myrp = 0.f;
  #pragma unroll
  for (int m = 0; m < 4; ++m)
    #pragma unroll
    for (int j = 0; j < 4; ++j)
      if (g16 == m * 4 + j) myrp = rp[m][j];
  atomicAdd(&rsum[r0 + (g16 >> 2) * 16 + (g16 & 3)], myrp);
}

// ---------------- K5: GEMM2 fused with the per-row pass (builds slot lists) ----------------
__global__ __launch_bounds__(256) void k5_fused(
    const unsigned short* __restrict__ ktbf, const unsigned short* __restrict__ ebf,
    const float* __restrict__ rsum, const float* __restrict__ csum,
    const float* __restrict__ qsum, const float* __restrict__ kn2,
    const float* __restrict__ ksm, int* __restrict__ cnt, int* __restrict__ list,
    float* __restrict__ gw, float* __restrict__ out) {
  __shared__ unsigned short As[128 * 32];
  __shared__ unsigned short Bs[128 * 32];
  int bid = blockIdx.x;                              // 2048
  int g = (bid & 7) * 64 + (bid >> 5);               // (b,nt); XCD siblings share B panel
  int b = g >> 5, nt = g & 31, dt = (bid >> 3) & 3;
  int tid = threadIdx.x;
  int lane = tid & 63, wid = tid >> 6;
  int wr = wid >> 1, wc = wid & 1;
  float4v acc[4][4];
  #pragma unroll
  for (int m = 0; m < 4; ++m)
    #pragma unroll
    for (int n = 0; n < 4; ++n) acc[m][n] = (float4v){0.f, 0.f, 0.f, 0.f};
  const unsigned short* Abase = ktbf + (size_t)dt * 128 * 512;
  size_t brow0 = (size_t)g * 128;
  int u0 = wid * 128 + lane, u1 = u0 + 64;
  int ra0 = u0 >> 2, ca0 = (u0 & 3) * 8;
  int ra1 = u1 >> 2, ca1 = (u1 & 3) * 8;
  for (int kt = 0; kt < 16; ++kt) {
    GLDS16(Abase + (size_t)ra0 * 512 + kt * 32 + ca0, &As[(wid * 2 + 0) * 512]);
    GLDS16(Abase + (size_t)ra1 * 512 + kt * 32 + ca1, &As[(wid * 2 + 1) * 512]);
    GLDS16(ebf + (brow0 + ra0) * 512 + kt * 32 + ca0, &Bs[(wid * 2 + 0) * 512]);
    GLDS16(ebf + (brow0 + ra1) * 512 + kt * 32 + ca1, &Bs[(wid * 2 + 1) * 512]);
    __syncthreads();
    short8v a[4], bb[4];
    const unsigned short* pa = As + (wr * 64 + (lane & 15)) * 32 + (lane >> 4) * 8;
    const unsigned short* pb = Bs + (wc * 64 + (lane & 15)) * 32 + (lane >> 4) * 8;
    #pragma unroll
    for (int m = 0; m < 4; ++m) a[m] = *(const short8v*)(pa + m * 512);
    #pragma unroll
    for (int n = 0; n < 4; ++n) bb[n] = *(const short8v*)(pb + n * 512);
    #pragma unroll
    for (int m = 0; m < 4; ++m)
      #pragma unroll
      for (int n = 0; n < 4; ++n)
        acc[m][n] = __builtin_amdgcn_mfma_f32_16x16x32_bf16(a[m], bb[n], acc[m][n], 0, 0, 0);
    __syncthreads();
  }
  // GEMM epilogue: out[b, 512 + d, hw], scaled by 1/rsum[col-row] (nt stores)
  {
    float* dst = out + (size_t)b * 4194304 + (size_t)512 * 4096;
    int d0 = dt * 128 + wr * 64 + (lane >> 4) * 4;
    int c0 = nt * 128 + wc * 64 + (lane & 15);
    float invc[4];
    #pragma unroll
    for (int n = 0; n < 4; ++n) invc[n] = 1.0f / rsum[b * 4096 + c0 + n * 16];
    #pragma unroll
    for (int m = 0; m < 4; ++m)
      #pragma unroll
      for (int n = 0; n < 4; ++n)
        #pragma unroll
        for (int j = 0; j < 4; ++j)
          __builtin_nontemporal_store(acc[m][n][j] * invc[n],
              &dst[(size_t)(d0 + m * 16 + j) * 4096 + (c0 + n * 16)]);
  }
  // Row phase: rows [g*128 + dt*32, +32), 8 per wave (Ebf rows are L2-hot)
  float4v cA = *(const float4v*)(csum + lane * 8);
  float4v cB = *(const float4v*)(csum + lane * 8 + 4);
  float4v rcA, rcB;
  #pragma unroll
  for (int j = 0; j < 4; ++j) { rcA[j] = 1.0f / cA[j]; rcB[j] = 1.0f / cB[j]; }
  float closs = 0.f, sloss = 0.f;
  const float S2 = 4.525483399593904f;   // 2*sqrt(512)*0.1
  int r_base = g * 128 + dt * 32 + wid * 8;
  for (int it = 0; it < 8; ++it) {
    int r = r_base + it;
    short8v eb = *(const short8v*)(ebf + (size_t)r * 512 + lane * 8);
    float e[8];
    #pragma unroll
    for (int j = 0; j < 8; ++j) e[j] = bf2f((unsigned short)eb[j]);
    float invr = 1.0f / rsum[r];          // exact f32 row sum from k3
    // top-2 (ties -> lower index)
    float v1 = -1.f, v2 = -2.f; int i1 = 0, i2 = 0;
    #pragma unroll
    for (int j = 0; j < 8; ++j) {
      float val = e[j]; int idx = lane * 8 + j;
      if (val > v1) { v2 = v1; i2 = i1; v1 = val; i1 = idx; }
      else if (val > v2) { v2 = val; i2 = idx; }
    }
    #pragma unroll
    for (int off = 1; off < 64; off <<= 1) {
      float ov1 = __shfl_xor(v1, off); int oi1 = __shfl_xor(i1, off);
      float ov2 = __shfl_xor(v2, off); int oi2 = __shfl_xor(i2, off);
      bool take = (ov1 > v1) || (ov1 == v1 && oi1 < i1);
      float av = take ? v1 : v2;  int ai = take ? i1 : i2;
      float bv = take ? ov2 : ov1; int bi = take ? oi2 : oi1;
      bool t2 = (bv > av) || (bv == av && bi < ai);
      v2 = t2 ? bv : av; i2 = t2 ? bi : ai;
      v1 = take ? ov1 : v1; i1 = take ? oi1 : i1;
    }
    float* SQrow = out + SQ_OFF + (size_t)r * 512;
    float* SMrow = out + SM_OFF + (size_t)r * 512;
    float4v sq0, sq1, sm0, sm1;
    #pragma unroll
    for (int j = 0; j < 4; ++j) {
      sq0[j] = e[j] * rcA[j];     sq1[j] = e[4 + j] * rcB[j];
      sm0[j] = e[j] * invr;       sm1[j] = e[4 + j] * invr;
    }
    __builtin_nontemporal_store(sq0, (float4v*)(SQrow + lane * 8));
    __builtin_nontemporal_store(sq1, (float4v*)(SQrow + lane * 8 + 4));
    __builtin_nontemporal_store(sm0, (float4v*)(SMrow + lane * 8));
    __builtin_nontemporal_store(sm1, (float4v*)(SMrow + lane * 8 + 4));
    // closed-form losses: ||q||=1, q·k_i = s*ln(E_i)
    float qs = qsum[r];
    float cp_row = 1.0f + kn2[i1] - S2 * __logf(v1);
    float dp2 = cp_row + 2e-6f * (qs - ksm[i1]) + 5.12e-10f;
    float cn_row = 1.0f + kn2[i2] - S2 * __logf(v2);
    float dn2 = cn_row + 2e-6f * (qs - ksm[i2]) + 5.12e-10f;
    closs += cp_row;
    sloss += fmaxf(sqrtf(dp2) - sqrtf(dn2) + 1.0f, 0.f);
    if (lane == 0) {
      gw[r] = v1 / csum[i1];
      int pos = atomicAdd(&cnt[i1], 1);
      if (pos < 1024) list[(i1 << 10) + pos] = r;
    }
  }
  if (lane == 0) {
    atomicAdd(out + SEP_OFF, sloss * (1.0f / 65536.0f));
    atomicAdd(out + COMP_OFF, closs * (1.0f / (65536.0f * 512.0f)));
  }
}

// ---------------- K4b: list-based segment gather + memory update ----------------
__global__ __launch_bounds__(512) void k4b_gather(
    const int* __restrict__ cnt, const int* __restrict__ list,
    const float* __restrict__ gw, const unsigned short* __restrict__ qbf,
    const float* __restrict__ keys, float* __restrict__ out) {
  __shared__ float red[8][512];
  __shared__ float wss[8];
  int m = blockIdx.x;                 // 512
  int tid = threadIdx.x, lane = tid & 63, wid = tid >> 6;
  int n = cnt[m]; if (n > 1024) n = 1024;
  float acc[8] = {0.f, 0.f, 0.f, 0.f, 0.f, 0.f, 0.f, 0.f};
  for (int idx = wid; idx < n; idx += 8) {
    int r = list[(m << 10) + idx];
    float wv = gw[r];
    short8v qv = *(const short8v*)(qbf + (size_t)r * 512 + lane * 8);
    #pragma unroll
    for (int j = 0; j < 8; ++j) acc[j] += wv * bf2f((unsigned short)qv[j]);
  }
  #pragma unroll
  for (int j = 0; j < 8; ++j) red[wid][lane * 8 + j] = acc[j];
  __syncthreads();
  int d0 = tid;                        // 0..511
  float s = 0.f;
  #pragma unroll
  for (int g = 0; g < 8; ++g) s += red[g][d0];
  float v = keys[(size_t)m * 512 + d0] * 0.999f + s * 0.001f;
  float ss = v * v;
  #pragma unroll
  for (int off = 1; off < 64; off <<= 1) ss += __shfl_xor(ss, off);
  if (lane == 0) wss[wid] = ss;
  __syncthreads();
  float tot = 0.f;
  #pragma unroll
  for (int g = 0; g < 8; ++g) tot += wss[g];
  float rsn = 1.0f / fmaxf(sqrtf(tot), 1e-12f);
  out[UM_OFF + (size_t)m * 512 + d0] = v * rsn;
}

extern "C" void kernel_launch(void* const* d_in, const int* in_sizes, int n_in,
                              void* d_out, int out_size, void* d_ws, size_t ws_size,
                              hipStream_t stream) {
  const float* query = (const float*)d_in[0];
  const float* keys  = (const float*)d_in[1];
  float* out = (float*)d_out;
  char* ws = (char*)d_ws;
  unsigned short* qbf  = (unsigned short*)(ws + WS_QBF);
  unsigned short* ebf  = (unsigned short*)(ws + WS_EBF);
  unsigned short* kbf  = (unsigned short*)(ws + WS_KBF);
  unsigned short* ktbf = (unsigned short*)(ws + WS_KTBF);
  float* gw   = (float*)(ws + WS_W);
  float* rsum = (float*)(ws + WS_RSUM);
  float* csum = (float*)(ws + WS_CSUM);
  float* kn2  = (float*)(ws + WS_KN2);
  float* ksm  = (float*)(ws + WS_KSM);
  int*   cnt  = (int*)(ws + WS_CNT);
  float* qsum = (float*)(ws + WS_QSUM);
  int*   list = (int*)(ws + WS_LIST);

  k01_prep_norm<<<dim3(1536), dim3(512), 0, stream>>>(
      query, keys, kbf, ktbf, csum, rsum, kn2, ksm, cnt, qbf, qsum, out);
  k3_gemm1<<<dim3(2048), dim3(256), 0, stream>>>(qbf, kbf, ebf, csum, rsum);
  k5_fused<<<dim3(2048), dim3(256), 0, stream>>>(
      ktbf, ebf, rsum, csum, qsum, kn2, ksm, cnt, list, gw, out);
  k4b_gather<<<dim3(512), dim3(512), 0, stream>>>(cnt, list, gw, qbf, keys, out);
}